// Round 4
// baseline (328.264 us; speedup 1.0000x reference)
//
#include <hip/hip_runtime.h>

// Problem constants (fixed by reference setup_inputs)
#define B_  8
#define T_  1000
#define F_  257
#define P_  (T_ * F_)               // 257000 floats per (T,F) plane
#define SQ3_2 0.8660254037844386f

#define THREADS 512
#define VEC     4
#define CHUNK   (THREADS * VEC)              // 2048 floats per block
#define NBLK    ((P_ + CHUNK - 1) / CHUNK)   // 126
#define XROWS   11                           // t halo rows: t_lo-2 .. t_lo+8
#define XCOLS   259                          // j = ff+1, ff = -1 .. 257
#define PP      65                           // page pitch (float2) = ceil(259/4)
// Page-interleaved x-halo layout: element (r, j) lives at float2 index
//   I(r,j) = (r*4 + (j&3))*PP + (j>>2)
// => a tap read at lane-stride 4 in j (VEC=4 threads) is lane-stride 1 in LDS
//    (contiguous ds_read_b64, conflict-free), fixing R2's 16-way conflict.
#define LDSN    (XROWS * 4 * PP)             // 2860 float2 = 22.9 KB

__global__ __launch_bounds__(THREADS)
void ccm_fused(const float* __restrict__ m, const float2* __restrict__ x,
               float2* __restrict__ out) {
    __shared__ float2 buf[LDSN];   // x halo (paged); reused for out staging

    const int b      = blockIdx.z;
    const int s      = blockIdx.x * CHUNK;   // first flat index owned
    const int send   = min(s + CHUNK, P_);
    const int t_lo   = s / F_;               // uniform per block
    const int t_base = t_lo - 2;
    const int tid    = threadIdx.x;

    // ---- Stage x halo into paged LDS layout ----
    // idx = j*XROWS + r, r fast: consecutive lanes read consecutive t
    // (x contiguous in t), 88 B per f-row.
    const float2* xb = x + (size_t)b * (F_ * T_);
    for (int idx = tid; idx < XROWS * XCOLS; idx += THREADS) {
        const int j  = idx / XROWS;
        const int r  = idx - j * XROWS;
        const int tt = t_base + r;
        const int ff = j - 1;
        float2 v = make_float2(0.f, 0.f);
        if (tt >= 0 && tt < T_ && ff >= 0 && ff < F_)
            v = xb[(size_t)ff * T_ + tt];
        buf[(r * 4 + (j & 3)) * PP + (j >> 2)] = v;
    }
    __syncthreads();

    const int  p0     = s + tid * VEC;       // multiple of 4; P_ is too
    const bool active = p0 < P_;             // p0<P_ => p0+3<P_ (P_%4==0)

    float accr[VEC], acci[VEC];
    #pragma unroll
    for (int e = 0; e < VEC; ++e) { accr[e] = 0.f; acci[e] = 0.f; }

    // Combined tap indices per q=c%3: tap(c,e) = buf[Cq[e] + (c/3)*4*PP]
    int C0[VEC], C1[VEC], C2[VEC];

    if (active) {
        int te = p0 / F_;
        int fe = p0 - te * F_;
        #pragma unroll
        for (int e = 0; e < VEC; ++e) {
            const int A  = (te - t_lo) * (4 * PP);
            const int j0 = fe;               // tap j = fe + q, q = c%3
            C0[e] = A + ((j0    ) & 3) * PP + ((j0    ) >> 2);
            C1[e] = A + ((j0 + 1) & 3) * PP + ((j0 + 1) >> 2);
            C2[e] = A + ((j0 + 2) & 3) * PP + ((j0 + 2) >> 2);
            if (++fe == F_) { fe = 0; ++te; }   // row-wrap handling
        }

        // ---- 27 aligned float4 m-loads (1 KB/wave), FMA into acc ----
        const float* mb = m + (size_t)b * 27 * P_ + p0;
        #pragma unroll
        for (int c = 0; c < 9; ++c) {
            const float4 m0 = *(const float4*)(mb + (size_t)(c)      * P_);
            const float4 m1 = *(const float4*)(mb + (size_t)(c + 9)  * P_);
            const float4 m2 = *(const float4*)(mb + (size_t)(c + 18) * P_);
            const int rowoff = (c / 3) * (4 * PP);   // folds into ds offset
            const float* f0v = (const float*)&m0;
            const float* f1v = (const float*)&m1;
            const float* f2v = (const float*)&m2;
            #pragma unroll
            for (int e = 0; e < VEC; ++e) {
                const float hr = f0v[e] - 0.5f * (f1v[e] + f2v[e]);
                const float hi = SQ3_2 * (f1v[e] - f2v[e]);
                const int   ci = (c % 3 == 0) ? C0[e] : (c % 3 == 1) ? C1[e] : C2[e];
                const float2 xv = buf[ci + rowoff];
                accr[e] = fmaf(hr,  xv.x, accr[e]);
                accr[e] = fmaf(-hi, xv.y, accr[e]);
                acci[e] = fmaf(hr,  xv.y, acci[e]);
                acci[e] = fmaf(hi,  xv.x, acci[e]);
            }
        }
    }

    __syncthreads();   // all taps consumed; reuse buf for output staging

    if (active) {
        int te = p0 / F_;
        int fe = p0 - te * F_;
        #pragma unroll
        for (int e = 0; e < VEC; ++e) {
            buf[(te - t_lo) * F_ + fe] = make_float2(accr[e], acci[e]);
            if (++fe == F_) { fe = 0; ++te; }
        }
    }
    __syncthreads();

    // ---- Transposed write-out: r fast => contiguous t per f-row ----
    float2* ob = out + (size_t)b * (F_ * T_);
    for (int idx = tid; idx < 9 * F_; idx += THREADS) {
        const int f = idx / 9;
        const int r = idx - f * 9;
        const int t = t_lo + r;
        const int p = t * F_ + f;
        if (p >= s && p < send)
            ob[(size_t)f * T_ + t] = buf[r * F_ + f];
    }
}

extern "C" void kernel_launch(void* const* d_in, const int* in_sizes, int n_in,
                              void* d_out, int out_size, void* d_ws, size_t ws_size,
                              hipStream_t stream) {
    const float*  m = (const float*)d_in[0];   // (B, 27, T, F) fp32
    const float2* x = (const float2*)d_in[1];  // (B, F, T, 2) fp32 -> float2
    float2* out = (float2*)d_out;              // (B, F, T, 2) fp32 -> float2

    dim3 mb(THREADS);
    dim3 mg(NBLK, 1, B_);                      // 126 x 1 x 8
    ccm_fused<<<mg, mb, 0, stream>>>(m, x, out);
}

// Round 6
// 327.223 us; speedup vs baseline: 1.0032x; 1.0032x over previous
//
#include <hip/hip_runtime.h>

// Problem constants (fixed by reference setup_inputs)
#define B_  8
#define T_  1000
#define F_  257
#define TP_ (T_ * F_)               // plane stride in floats
#define SQ3_2 0.8660254037844386f

#define THREADS 512
#define TT 16                       // t-tile (2 outputs per thread: t, t+8)
#define FW 67                       // xls cols: ff = f0-1 .. f0+65
#define XR 18                       // xls rows: tt = t0-2 .. t0+15

// ---------------------------------------------------------------------------
// R3 structure with t-tile doubled to 16 (2 outputs/thread):
//   - scalar m loads, coalesced 256 B/wave (proven best pattern; R2/R4's wide
//     loads regressed), 54 loads/thread.
//   - conflict-free lane-stride-1 LDS taps.
//   - blocks 4000 -> 2016: halved barrier/stage/write overhead per output.
//   - out writes are full 128 B-aligned lines (16 t x 8 B, t0 multiple of 16).
//   - grid.x = 4: f=256 column handled by 16 threads of wave 0 in bx==3.
// ---------------------------------------------------------------------------
__global__ __launch_bounds__(THREADS)
void ccm_fused(const float* __restrict__ m, const float2* __restrict__ x,
               float2* __restrict__ out) {
    __shared__ float2 xls[XR * FW];    // 9.6 KB
    __shared__ float2 stage[TT][66];   // 8.4 KB (65 cols used)

    const int  b    = blockIdx.z;
    const int  f0   = blockIdx.x * 64;
    const int  t0   = blockIdx.y * TT;
    const bool LAST = (blockIdx.x == 3);
    const int  tid  = threadIdx.x;
    const int  lf   = tid & 63;        // lane's f within tile (stride-1)
    const int  lt   = tid >> 6;        // lane's t within tile (0..7)
    const int  f    = f0 + lf;         // always <= 255
    const int  t_a  = t0 + lt;         // always < T_ (t0 <= 992, lt <= 7)
    const int  t_b  = t_a + 8;         // may be >= T_ in last t-tile
    const bool vb   = (t_b < T_);      // wave-uniform (one lt per wave)

    // ---- Stage x halo as float4 (2 consecutive t per load) ----
    // idx = j*9 + q; tt = t0-2+2q is even, rows 8000 B => 16 B aligned.
    // t0-2 even and T_ even => a float4 pair never straddles the 0/T_ edge.
    const float2* xb = x + (size_t)b * (F_ * T_);
    for (int idx = tid; idx < FW * 9; idx += THREADS) {
        const int j  = idx / 9;
        const int q  = idx - j * 9;
        const int ff = f0 + j - 1;
        const int tt = t0 - 2 + 2 * q;
        float2 v0 = make_float2(0.f, 0.f), v1 = v0;
        if (ff >= 0 && ff < F_ && tt >= 0 && tt < T_) {
            const float4 v = *(const float4*)(xb + (size_t)ff * T_ + tt);
            v0 = make_float2(v.x, v.y);
            v1 = make_float2(v.z, v.w);
        }
        xls[(2 * q)     * FW + j] = v0;
        xls[(2 * q + 1) * FW + j] = v1;
    }
    __syncthreads();

    // ---- Main compute: 54 scalar m loads, conflict-free LDS taps ----
    float ar_a = 0.f, ai_a = 0.f, ar_b = 0.f, ai_b = 0.f;
    {
        const float* mb = m + ((size_t)b * 27 * T_ + t_a) * F_ + f;
        #pragma unroll
        for (int c = 0; c < 9; ++c) {
            const int dt = c / 3, q = c % 3;
            {   // row t_a
                const float m0 = mb[(size_t)(c)      * TP_];
                const float m1 = mb[(size_t)(c + 9)  * TP_];
                const float m2 = mb[(size_t)(c + 18) * TP_];
                const float hr = m0 - 0.5f * (m1 + m2);
                const float hi = SQ3_2 * (m1 - m2);
                const float2 xv = xls[(lt + dt) * FW + (lf + q)];
                ar_a = fmaf(hr,  xv.x, ar_a);
                ar_a = fmaf(-hi, xv.y, ar_a);
                ai_a = fmaf(hr,  xv.y, ai_a);
                ai_a = fmaf(hi,  xv.x, ai_a);
            }
            if (vb) {   // row t_b (wave-uniform branch)
                const float m0 = mb[(size_t)(c)      * TP_ + 8 * F_];
                const float m1 = mb[(size_t)(c + 9)  * TP_ + 8 * F_];
                const float m2 = mb[(size_t)(c + 18) * TP_ + 8 * F_];
                const float hr = m0 - 0.5f * (m1 + m2);
                const float hi = SQ3_2 * (m1 - m2);
                const float2 xv = xls[(lt + 8 + dt) * FW + (lf + q)];
                ar_b = fmaf(hr,  xv.x, ar_b);
                ar_b = fmaf(-hi, xv.y, ar_b);
                ai_b = fmaf(hr,  xv.y, ai_b);
                ai_b = fmaf(hi,  xv.x, ai_b);
            }
        }
    }
    stage[lt][lf]     = make_float2(ar_a, ai_a);
    stage[lt + 8][lf] = make_float2(ar_b, ai_b);   // never read if !vb

    // ---- Extra column f=256 (bx==3 only): 16 threads of wave 0 ----
    if (LAST && tid < TT && (t0 + tid) < T_) {
        float ar = 0.f, ai = 0.f;
        const float* mb2 = m + ((size_t)b * 27 * T_ + (t0 + tid)) * F_ + 256;
        #pragma unroll
        for (int c = 0; c < 9; ++c) {
            const float m0 = mb2[(size_t)(c)      * TP_];
            const float m1 = mb2[(size_t)(c + 9)  * TP_];
            const float m2 = mb2[(size_t)(c + 18) * TP_];
            const float hr = m0 - 0.5f * (m1 + m2);
            const float hi = SQ3_2 * (m1 - m2);
            const float2 xv = xls[(tid + c / 3) * FW + (64 + c % 3)];
            ar = fmaf(hr,  xv.x, ar);
            ar = fmaf(-hi, xv.y, ar);
            ai = fmaf(hr,  xv.y, ai);
            ai = fmaf(hi,  xv.x, ai);
        }
        stage[tid][64] = make_float2(ar, ai);
    }
    __syncthreads();

    // ---- Transposed write-out: wt fast => 128 B aligned lines ----
    const int NC = LAST ? 65 : 64;
    float2* ob = out + (size_t)b * (F_ * T_);
    for (int idx = tid; idx < NC * TT; idx += THREADS) {
        const int wf = idx >> 4;       // 0..64
        const int wt = idx & 15;       // 0..15
        if (t0 + wt < T_)
            ob[(size_t)(f0 + wf) * T_ + (t0 + wt)] = stage[wt][wf];
    }
}

extern "C" void kernel_launch(void* const* d_in, const int* in_sizes, int n_in,
                              void* d_out, int out_size, void* d_ws, size_t ws_size,
                              hipStream_t stream) {
    const float*  m = (const float*)d_in[0];   // (B, 27, T, F) fp32
    const float2* x = (const float2*)d_in[1];  // (B, F, T, 2) fp32 -> float2
    float2* out = (float2*)d_out;              // (B, F, T, 2) fp32 -> float2

    dim3 mb(THREADS);
    dim3 mg(4, (T_ + TT - 1) / TT, B_);        // 4 x 63 x 8
    ccm_fused<<<mg, mb, 0, stream>>>(m, x, out);
}